// Round 4
// baseline (322.132 us; speedup 1.0000x reference)
//
#include <hip/hip_runtime.h>

// AdaMoeLayer: B=8,S=4096,D=512,E=8 -> T=32768 tokens
// Round 6: counted-vmcnt 3-slot pipeline (T3/T4) on the R5 structure.
//  - 512 threads, 128x256 tile, BK=64, 3-slot LDS ring, 2-step load lookahead.
//  - End-of-step: s_waitcnt vmcnt(6) (drain OLDER batch only) + raw s_barrier
//    (no vmcnt(0) drain -> loads span ~2 compute steps).
//  - Expert fold (acc += w*tmp) every 8 steps; bias folded in epilogue.
//  - T5 setprio around MFMA cluster. XOR-swizzled LDS (conflict-free, R5-proven).

#define T_TOKENS 32768
#define DDIM 512
#define KDIM 4096
#define SLOTA 8192   // ushorts per A slot (128*64)
#define SLOTB 16384  // ushorts per B slot (256*64)

typedef __attribute__((ext_vector_type(8))) short short8;
typedef __attribute__((ext_vector_type(4))) float floatx4;
typedef __bf16 bf16x2 __attribute__((ext_vector_type(2)));

__device__ __forceinline__ unsigned short f2bf(float f) {
    unsigned int u = __float_as_uint(f);
    u += 0x7FFFu + ((u >> 16) & 1u);   // RNE
    return (unsigned short)(u >> 16);
}

__device__ __forceinline__ unsigned int pk2(float a, float b) {
#if __has_builtin(__builtin_amdgcn_cvt_pk_bf16_f32)
    bf16x2 v = __builtin_amdgcn_cvt_pk_bf16_f32(a, b);
    return __builtin_bit_cast(unsigned int, v);
#else
    return (unsigned int)f2bf(a) | ((unsigned int)f2bf(b) << 16);
#endif
}

__device__ __forceinline__ void async_copy16(const void* g, void* l) {
    __builtin_amdgcn_global_load_lds(
        (const __attribute__((address_space(1))) void*)g,
        (__attribute__((address_space(3))) void*)l, 16, 0, 0);
}

// ------- Kernel 1: gating (fp32) -> wbuf[T,8]  +  x -> bf16 Xbf[T,512] ------
__global__ __launch_bounds__(256) void gating_cvt(
    const float* __restrict__ x, const float* __restrict__ Wg,
    const float* __restrict__ bg, const float* __restrict__ Wt,
    const float* __restrict__ bt, float* __restrict__ wbuf,
    unsigned short* __restrict__ Xbf)
{
    __shared__ float sW[512 * 12];  // [d][12]: e<8 gate cols, e==8 thr col
    const int tid = threadIdx.x;
    for (int i = tid; i < 512 * 9; i += 256) {
        int d = i / 9, e = i - d * 9;
        sW[d * 12 + e] = (e < 8) ? Wg[d * 8 + e] : Wt[d];
    }
    __syncthreads();

    const int t = blockIdx.x * 64 + (tid >> 2);
    const int q = tid & 3;
    float g[9];
#pragma unroll
    for (int e = 0; e < 9; ++e) g[e] = 0.f;

    const float4* xr = (const float4*)(x + (size_t)t * 512 + q * 128);
    for (int i = 0; i < 32; ++i) {
        float4 v = xr[i];
        float xv[4] = {v.x, v.y, v.z, v.w};
        const float* wp = &sW[(q * 128 + i * 4) * 12];
#pragma unroll
        for (int c = 0; c < 4; ++c) {
            const float* w = wp + c * 12;
#pragma unroll
            for (int e = 0; e < 9; ++e) g[e] = fmaf(xv[c], w[e], g[e]);
        }
    }
#pragma unroll
    for (int e = 0; e < 9; ++e) {
        g[e] += __shfl_xor(g[e], 1);
        g[e] += __shfl_xor(g[e], 2);
    }
    if (q == 0) {
#pragma unroll
        for (int e = 0; e < 8; ++e) g[e] += bg[e];
        g[8] += bt[0];
        float m = g[0];
#pragma unroll
        for (int e = 1; e < 8; ++e) m = fmaxf(m, g[e]);
        float s = 0.f;
        float p[8];
#pragma unroll
        for (int e = 0; e < 8; ++e) { p[e] = __expf(g[e] - m); s += p[e]; }
        const float inv = 1.f / s;
        const float thr = 0.25f / (1.f + __expf(-g[8]));
        float w8[8];
        float ws = 0.f;
#pragma unroll
        for (int e = 0; e < 8; ++e) {
            float a = p[e] * inv - thr;
            w8[e] = a > 0.f ? a : 0.f;
            ws += w8[e];
        }
        if (ws == 0.f) ws = 1.f;
        const float invw = 1.f / ws;
        float4 o0, o1;
        o0.x = w8[0] * invw; o0.y = w8[1] * invw; o0.z = w8[2] * invw; o0.w = w8[3] * invw;
        o1.x = w8[4] * invw; o1.y = w8[5] * invw; o1.z = w8[6] * invw; o1.w = w8[7] * invw;
        float4* op = (float4*)(wbuf + (size_t)t * 8);
        op[0] = o0;
        op[1] = o1;
    }

    // conversion pass: this block's 64 tokens = 32768 floats, coalesced (L2-hot)
    const size_t base = (size_t)blockIdx.x * 64 * 512;
    const float4* xs = (const float4*)(x + base);
    uint2* xd = (uint2*)(Xbf + base);
#pragma unroll 4
    for (int it = 0; it < 32; ++it) {
        float4 v = xs[it * 256 + tid];
        uint2 pk;
        pk.x = pk2(v.x, v.y);
        pk.y = pk2(v.z, v.w);
        xd[it * 256 + tid] = pk;
    }
}

// ------------- Kernel 2: build Bt[512][4096] bf16 (transpose W_exp) --------
__global__ __launch_bounds__(256) void build_bt(
    const float* __restrict__ Wexp, unsigned short* __restrict__ Bt)
{
    __shared__ float tile[64][65];
    const int k0 = blockIdx.x * 64;
    const int n0 = blockIdx.y * 64;
    const int tid = threadIdx.x;
    const int r = tid >> 4, cq = tid & 15;
#pragma unroll
    for (int p = 0; p < 4; ++p) {
        const int rr = p * 16 + r;
        const float4 v = *(const float4*)(Wexp + (size_t)(k0 + rr) * 512 + n0 + cq * 4);
        tile[rr][cq * 4 + 0] = v.x;
        tile[rr][cq * 4 + 1] = v.y;
        tile[rr][cq * 4 + 2] = v.z;
        tile[rr][cq * 4 + 3] = v.w;
    }
    __syncthreads();
    const int rn = tid >> 2;  // output row (n), 0..63
    const int kq = tid & 3;   // 16-wide k chunk
    alignas(16) unsigned short buf[16];
#pragma unroll
    for (int j = 0; j < 16; ++j) buf[j] = f2bf(tile[kq * 16 + j][rn]);
    unsigned short* dst = Bt + (size_t)(n0 + rn) * KDIM + k0 + kq * 16;
    *(uint4*)(dst) = *(const uint4*)(buf);
    *(uint4*)(dst + 8) = *(const uint4*)(buf + 8);
}

// ------------- Kernel 3: main GEMM, 128x256 tile, 3-slot counted pipeline --
// LDS element (row,k) at row*64 + ((k/8 ^ (row&7))*8)+k%8 (ushort index).
// Staged by global_load_lds with lane->global chunk perm cg=(lane&7)^(lane>>3).
// Step s = e*8+ks. Loads for step s+2 issued at step s; end-of-step waits
// vmcnt(6): drains only the s+1 batch (6 older loads), newest 6 stay in flight.
__global__ __launch_bounds__(512, 2) void moe_gemm(
    const unsigned short* __restrict__ Xbf, const float* __restrict__ wbuf,
    const float* __restrict__ bexp, const unsigned short* __restrict__ Bt,
    float* __restrict__ out)
{
    __shared__ alignas(16) unsigned short As[3 * 128 * 64];  // 48 KB
    __shared__ alignas(16) unsigned short Bs[3 * 256 * 64];  // 96 KB
    __shared__ float sWbT[8 * 128];                          // 4 KB, [e][row]

    const int tid = threadIdx.x;
    const int wave = tid >> 6;      // 0..7
    const int lane = tid & 63;
    const int wm = wave >> 2;       // 0..1: 64-row half
    const int wn = wave & 3;        // 0..3: 64-col quarter
    const int lm = lane & 15;
    const int lq = lane >> 4;
    const int brow = lane >> 3;
    const int cg = (lane & 7) ^ brow;  // lane->global chunk permutation

    // XCD co-location: hw XCD = lin%8; the 2 n-blocks of a t-tile are
    // consecutive j (share the Xbf t-slice in that XCD's L2).
    const int lin = blockIdx.x;
    const int g = lin & 7;
    const int j_ = lin >> 3;
    const int t0 = (g * 32 + (j_ >> 1)) * 128;
    const int n0 = (j_ & 1) * 256;

    // sWbT[e][row] = wbuf[t0+row][e]  (transposed so fold reads are b128)
    {
        const int row = tid & 127, q = tid >> 7;  // q = 0..3
        const float2 w2 = *(const float2*)(wbuf + (size_t)(t0 + row) * 8 + q * 2);
        sWbT[(q * 2 + 0) * 128 + row] = w2.x;
        sWbT[(q * 2 + 1) * 128 + row] = w2.y;
    }

    // 6 loads/thread/step: 2 for A (128 rows), 4 for B (256 rows)
#define STAGE(s_, slot_)                                                        \
    {                                                                           \
        const int d0_ = ((s_) & 7) << 6;                                        \
        _Pragma("unroll")                                                       \
        for (int i = 0; i < 2; ++i)                                             \
            async_copy16(Xbf + (size_t)(t0 + wave * 16 + i * 8 + brow) * 512 + d0_ + cg * 8, \
                         As + (slot_) * SLOTA + (wave * 16 + i * 8) * 64);      \
        const int k0_ = (s_) << 6;                                              \
        _Pragma("unroll")                                                       \
        for (int i = 0; i < 4; ++i)                                             \
            async_copy16(Bt + (size_t)(n0 + wave * 32 + i * 8 + brow) * KDIM + k0_ + cg * 8, \
                         Bs + (slot_) * SLOTB + (wave * 32 + i * 8) * 64);      \
    }

    // prologue: slots 0 and 1 staged; full drain (also covers sWbT ds_writes)
    STAGE(0, 0);
    STAGE(1, 1);
    __syncthreads();

    floatx4 acc[4][4], tmp[4][4];
#pragma unroll
    for (int i = 0; i < 4; ++i)
#pragma unroll
        for (int j = 0; j < 4; ++j) {
            acc[i][j] = (floatx4){0.f, 0.f, 0.f, 0.f};
            tmp[i][j] = (floatx4){0.f, 0.f, 0.f, 0.f};
        }

    int sl = 0;  // slot holding step s
    for (int s = 0; s < 64; ++s) {
        // ---- issue loads for step s+2 into slot (s+2)%3 ----
        if (s < 62) {
            const int sl2 = (sl >= 1) ? sl - 1 : 2;  // (sl+2)%3
            STAGE(s + 2, sl2);
        }
        // ---- compute step s from slot sl ----
        const unsigned short* Ab = As + sl * SLOTA;
        const unsigned short* Bb = Bs + sl * SLOTB;
        __builtin_amdgcn_s_setprio(1);
#pragma unroll
        for (int kk = 0; kk < 2; ++kk) {
            const int ch = kk * 4 + lq;
            short8 a[4], b[4];
#pragma unroll
            for (int i = 0; i < 4; ++i) {
                const int row = wm * 64 + i * 16 + lm;
                a[i] = *(const short8*)(Ab + row * 64 + ((ch ^ (row & 7)) << 3));
            }
#pragma unroll
            for (int j = 0; j < 4; ++j) {
                const int row = wn * 64 + j * 16 + lm;
                b[j] = *(const short8*)(Bb + row * 64 + ((ch ^ (row & 7)) << 3));
            }
#pragma unroll
            for (int i = 0; i < 4; ++i)
#pragma unroll
                for (int j = 0; j < 4; ++j)
                    tmp[i][j] = __builtin_amdgcn_mfma_f32_16x16x32_bf16(
                        a[i], b[j], tmp[i][j], 0, 0, 0);
        }
        __builtin_amdgcn_s_setprio(0);
        // ---- expert boundary: fold acc += w[t,e]*tmp, reinit tmp ----
        if ((s & 7) == 7) {
            const int e = s >> 3;
#pragma unroll
            for (int i = 0; i < 4; ++i) {
                const float4 wq = *(const float4*)(sWbT + e * 128 + wm * 64 + i * 16 + lq * 4);
#pragma unroll
                for (int j = 0; j < 4; ++j) {
                    acc[i][j][0] = fmaf(wq.x, tmp[i][j][0], acc[i][j][0]);
                    acc[i][j][1] = fmaf(wq.y, tmp[i][j][1], acc[i][j][1]);
                    acc[i][j][2] = fmaf(wq.z, tmp[i][j][2], acc[i][j][2]);
                    acc[i][j][3] = fmaf(wq.w, tmp[i][j][3], acc[i][j][3]);
                    tmp[i][j] = (floatx4){0.f, 0.f, 0.f, 0.f};
                }
            }
        }
        // ---- counted drain: only the step-s+1 batch must have landed ----
        if (s < 62) {
            asm volatile("s_waitcnt vmcnt(6)" ::: "memory");
        } else if (s == 62) {
            asm volatile("s_waitcnt vmcnt(0)" ::: "memory");
        }
        if (s < 63) __builtin_amdgcn_s_barrier();
        sl = (sl >= 2) ? 0 : sl + 1;
    }

    // epilogue: out = acc + sum_e w[t,e]*b_exp[e,col]
    float bc[4][8];
#pragma unroll
    for (int j = 0; j < 4; ++j) {
        const int col = n0 + wn * 64 + j * 16 + lm;
#pragma unroll
        for (int e = 0; e < 8; ++e) bc[j][e] = bexp[e * 512 + col];
    }
#pragma unroll
    for (int i = 0; i < 4; ++i)
#pragma unroll
        for (int r = 0; r < 4; ++r) {
            const int rowl = wm * 64 + i * 16 + lq * 4 + r;
            const float4 w0 = *(const float4*)(wbuf + (size_t)(t0 + rowl) * 8);
            const float4 w1 = *(const float4*)(wbuf + (size_t)(t0 + rowl) * 8 + 4);
            float* op = out + (size_t)(t0 + rowl) * 512 + n0 + wn * 64 + lm;
#pragma unroll
            for (int j = 0; j < 4; ++j) {
                float bias = w0.x * bc[j][0];
                bias = fmaf(w0.y, bc[j][1], bias);
                bias = fmaf(w0.z, bc[j][2], bias);
                bias = fmaf(w0.w, bc[j][3], bias);
                bias = fmaf(w1.x, bc[j][4], bias);
                bias = fmaf(w1.y, bc[j][5], bias);
                bias = fmaf(w1.z, bc[j][6], bias);
                bias = fmaf(w1.w, bc[j][7], bias);
                op[j * 16] = acc[i][j][r] + bias;
            }
        }
#undef STAGE
}

extern "C" void kernel_launch(void* const* d_in, const int* in_sizes, int n_in,
                              void* d_out, int out_size, void* d_ws, size_t ws_size,
                              hipStream_t stream) {
    const float* x   = (const float*)d_in[0];
    const float* Wg  = (const float*)d_in[1];
    const float* bg  = (const float*)d_in[2];
    const float* Wt  = (const float*)d_in[3];
    const float* bt  = (const float*)d_in[4];
    const float* Wex = (const float*)d_in[5];
    const float* bex = (const float*)d_in[6];
    float* out = (float*)d_out;

    // ws layout: Xbf bf16 [32768][512] = 32 MB; Bt bf16 [512][4096] = 4 MB;
    //            wbuf fp32 [32768][8] = 1 MB.  Total 37 MB.
    unsigned short* Xbf = (unsigned short*)d_ws;
    unsigned short* Bt  = (unsigned short*)((char*)d_ws + (size_t)T_TOKENS * DDIM * 2);
    float* wbuf = (float*)((char*)d_ws + (size_t)T_TOKENS * DDIM * 2
                                       + (size_t)DDIM * KDIM * 2);

    gating_cvt<<<T_TOKENS / 64, 256, 0, stream>>>(x, Wg, bg, Wt, bt, wbuf, Xbf);
    build_bt<<<dim3(KDIM / 64, DDIM / 64), 256, 0, stream>>>(Wex, Bt);
    moe_gemm<<<512, 512, 0, stream>>>(Xbf, wbuf, bex, Bt, out);
}